// Round 2
// baseline (309.921 us; speedup 1.0000x reference)
//
#include <hip/hip_runtime.h>

#define N_PTS 20000
#define DIMS  128
#define A_CNT 1024
#define KNEG  10
#define NTILES 157              // ceil(20000/128)
#define NCHUNK (NTILES * 16)    // 2512 chunk-of-8 slots per (side, anchor)
#define NCHUNK_REAL 2500        // 20000/8 — chunks >=2500 are pure padding
#define BIGV  1e18f
#define BIGI  0x7F000000
#define CAND_CAP 768
#define PT_CAP   768

// v_sad_u8: d = c + sum_{i=0..3} |a.byte[i] - b.byte[i]|  (4 dims per VALU op)
__device__ __forceinline__ unsigned int sad_u8(unsigned int a, unsigned int b, unsigned int c) {
#if __has_builtin(__builtin_amdgcn_sad_u8)
    return __builtin_amdgcn_sad_u8(a, b, c);
#else
    unsigned int d;
    asm("v_sad_u8 %0, %1, %2, %3" : "=v"(d) : "v"(a), "v"(b), "v"(c));
    return d;
#endif
}

// ---------------------------------------------------------------------------
// absmax over both fp32 arrays (bit-pattern atomicMax valid for non-neg fp32)
// ---------------------------------------------------------------------------
__global__ void absmax_kernel(const float* __restrict__ a, const float* __restrict__ b,
                              unsigned int* __restrict__ amax) {
    const int n4 = N_PTS * DIMS / 4;
    const int stride = gridDim.x * blockDim.x;
    float m = 0.f;
    for (int i = blockIdx.x * blockDim.x + threadIdx.x; i < 2 * n4; i += stride) {
        const float4 v = (i < n4) ? ((const float4*)a)[i] : ((const float4*)b)[i - n4];
        m = fmaxf(m, fmaxf(fmaxf(fabsf(v.x), fabsf(v.y)), fmaxf(fabsf(v.z), fabsf(v.w))));
    }
#pragma unroll
    for (int s = 1; s < 64; s <<= 1) m = fmaxf(m, __shfl_xor(m, s, 64));
    if ((threadIdx.x & 63) == 0) atomicMax(amax, __float_as_uint(m));
}

// ---------------------------------------------------------------------------
// quantize q = rint(127*v/M + 127) in [0,254]; also emit per-row residual sum
// R = sum_d |q_d - (s*v_d+127)| + 1.0 margin, and global Rmax.
// 8 threads per row, 16 dims each. Both sides fused via blockIdx.y.
// ---------------------------------------------------------------------------
__global__ void quantR_kernel(const float* __restrict__ o1, const float* __restrict__ o2,
                              unsigned int* __restrict__ q1, unsigned int* __restrict__ q2,
                              float* __restrict__ Ra, float* __restrict__ Rb,
                              const unsigned int* __restrict__ amaxBits,
                              unsigned int* __restrict__ rmaxBits) {
    const int side = blockIdx.y;
    const float* src = side ? o2 : o1;
    unsigned int* dst = side ? q2 : q1;
    float* Rrow = side ? Rb : Ra;
    const int g = blockIdx.x * 256 + threadIdx.x;
    const int row = g >> 3;
    const int sub = g & 7;
    if (row >= N_PTS) return;
    const float M = __uint_as_float(*amaxBits);
    const float s = 127.0f / M;
    const float4* s4 = (const float4*)(src + (size_t)row * DIMS + sub * 16);
    unsigned int* d = dst + (size_t)row * 32 + sub * 4;
    float rs = 0.f;
#pragma unroll
    for (int m = 0; m < 4; ++m) {
        const float4 v = s4[m];
        const float f0 = v.x * s + 127.0f, f1 = v.y * s + 127.0f;
        const float f2 = v.z * s + 127.0f, f3 = v.w * s + 127.0f;
        const float q0 = rintf(f0), q1v = rintf(f1), q2v = rintf(f2), q3 = rintf(f3);
        rs += fabsf(q0 - f0) + fabsf(q1v - f1) + fabsf(q2v - f2) + fabsf(q3 - f3);
        d[m] = (unsigned int)q0 | ((unsigned int)q1v << 8) |
               ((unsigned int)q2v << 16) | ((unsigned int)q3 << 24);
    }
    rs += __shfl_xor(rs, 1, 64);
    rs += __shfl_xor(rs, 2, 64);
    rs += __shfl_xor(rs, 4, 64);
    if (sub == 0) {
        const float R = rs + 1.0f;   // margin for fp rounding in s*v
        Rrow[row] = R;
        atomicMax(rmaxBits, __float_as_uint(R));
    }
}

// ---------------------------------------------------------------------------
// SAD distance kernel: 128 anchors x 128 points per block, 8x8 per thread.
// Round-1 analysis: the 4x8 variant was LDS-pipe-bound (12 ds_read_b128 per
// 128 sads; LDS demand ~2.2x VALU demand). 8x8 doubles arithmetic intensity
// (16 reads per 256 sads). acc 64 + frags 64 VGPR fits the 256-reg budget at
// __launch_bounds__(256,2) with NO AGPR round-trips (the old "64-acc tax" was
// the 128-reg cap at (256,4) spilling acc to AGPRs, unreadable by v_sad_u8).
// LDS: sA 128x32 + sP 128x32 uints (32KB); block b of row r at slot
// (b + (r>>3)) & 7 -> frag reads worst 2-way (free).
// ---------------------------------------------------------------------------
__global__ __launch_bounds__(256, 2)
void dist_sad_kernel(const unsigned int* __restrict__ q1, const unsigned int* __restrict__ q2,
                     const int* __restrict__ anchor1, const int* __restrict__ anchor2,
                     unsigned short* __restrict__ minOut) {
    __shared__ unsigned int sA[128 * 32];
    __shared__ unsigned int sP[128 * 32];

    const int tile = blockIdx.x;    // 0..156
    const int ag   = blockIdx.y;    // 0..7 (groups of 128 anchors)
    const int side = blockIdx.z;    // 0..1

    const unsigned int* aData = side ? q2 : q1;
    const unsigned int* pData = side ? q1 : q2;
    const int*          aIdx  = side ? anchor2 : anchor1;

    const int tid = threadIdx.x;
    const int tx = tid & 15;        // point chunk (8 pts)
    const int ty = tid >> 4;        // anchor chunk (8 anchors)

    // staging: 128 rows each, 2 threads/row, 4 uint4 each, for both sA and sP
    {
        const int r = tid >> 1;
        const int h = tid & 1;
        const int rot = r >> 3;
        const unsigned int* aRow = aData + (size_t)aIdx[ag * 128 + r] * 32;
        const uint4* aRow4 = (const uint4*)aRow + h * 4;
        const int prow = tile * 128 + r;
        const bool pvalid = prow < N_PTS;
        const uint4* pRow4 = (const uint4*)(pData + (size_t)prow * 32) + h * 4;
#pragma unroll
        for (int j = 0; j < 4; ++j) {
            const int blk = h * 4 + j;
            const int slot = ((blk + rot) & 7) << 2;
            *(uint4*)&sA[r * 32 + slot] = aRow4[j];
            const uint4 v = pvalid ? pRow4[j]
                                   : make_uint4(0xFFFFFFFFu, 0xFFFFFFFFu, 0xFFFFFFFFu, 0xFFFFFFFFu);
            *(uint4*)&sP[r * 32 + slot] = v;
        }
    }
    __syncthreads();

    unsigned int acc[8][8];
#pragma unroll
    for (int i = 0; i < 8; ++i)
#pragma unroll
        for (int j = 0; j < 8; ++j) acc[i][j] = 0u;

    const int ty8 = ty * 8;
    const int tx8 = tx * 8;

#pragma unroll 2
    for (int bk = 0; bk < 8; ++bk) {
        uint4 A[8], P[8];
        const int aslot = ((bk + ty) & 7) << 2;   // rot(ty*8+i) = ty
        const int pslot = ((bk + tx) & 7) << 2;   // rot(tx*8+j) = tx
#pragma unroll
        for (int i = 0; i < 8; ++i) A[i] = *(const uint4*)&sA[(ty8 + i) * 32 + aslot];
#pragma unroll
        for (int j = 0; j < 8; ++j) P[j] = *(const uint4*)&sP[(tx8 + j) * 32 + pslot];
#pragma unroll
        for (int i = 0; i < 8; ++i)
#pragma unroll
            for (int j = 0; j < 8; ++j) {
                unsigned int s = sad_u8(A[i].x, P[j].x, acc[i][j]);
                s = sad_u8(A[i].y, P[j].y, s);
                s = sad_u8(A[i].z, P[j].z, s);
                acc[i][j] = sad_u8(A[i].w, P[j].w, s);
            }
    }

    const size_t outBase = (size_t)side * A_CNT * NCHUNK;
#pragma unroll
    for (int i = 0; i < 8; ++i) {
        unsigned int m = min(min(min(acc[i][0], acc[i][1]), min(acc[i][2], acc[i][3])),
                             min(min(acc[i][4], acc[i][5]), min(acc[i][6], acc[i][7])));
        minOut[outBase + (size_t)(ag * 128 + ty8 + i) * NCHUNK + tile * 16 + tx] =
            (unsigned short)m;
    }
}

// ---------------------------------------------------------------------------
// select: one 256-thread block (4 waves) per (side, anchor).
//  A: block-min m1 of chunk minima, then counted threshold search: find E with
//     |{c : chunkmin[c] <= E}| >= 10 (3 bisection steps tighten E to within 24
//     of the true 10th-smallest). Replaces the ~3K-VALU/thread sorted-insert
//     merge machinery (round-1 counters: VALUBusy 56% = 7.5K insts/wave, most
//     of it Phase A) with ~250 VALU.
//     Correctness: count(E)>=10 -> >=10 chunks (hence points) with d_int <= E
//     -> s*D10 <= E+Ra+Rmax -> top-10 p: d_int(p) <= E + 2(Ra+Rmax).
//  thr = E + 2*R_a + 2*Rmax + 4.
//  B: candidate chunks; C: per-point u8 SAD filter (4 chunks in flight/wave);
//  D: exact fp32 recompute, 4 threads/point, anchor row in REGISTERS
//     (aRowF LDS was a 4-way bank alias); E: rank-count top-10 -> loss. Exact.
// ---------------------------------------------------------------------------
__global__ __launch_bounds__(256, 4)
void select_kernel(const float* __restrict__ out1, const float* __restrict__ out2,
                   const unsigned int* __restrict__ q1, const unsigned int* __restrict__ q2,
                   const int* __restrict__ anchor1, const int* __restrict__ anchor2,
                   const unsigned short* __restrict__ minIn,
                   const float* __restrict__ R1, const float* __restrict__ R2,
                   const unsigned int* __restrict__ rmaxBits, float* __restrict__ out) {
    const int bid = blockIdx.x;          // 0..2047
    const int side = bid >> 10;
    const int ai = bid & 1023;
    const int tid = threadIdx.x;
    const int lane = tid & 63;
    const int wv = tid >> 6;

    const float* aDataF = side ? out2 : out1;
    const float* pDataF = side ? out1 : out2;
    const unsigned int* aDataQ = side ? q2 : q1;
    const unsigned int* pDataQ = side ? q1 : q2;
    const float* Ranc = side ? R2 : R1;
    const int* aIdx = side ? anchor2 : anchor1;

    __shared__ int candCount, pointCount;
    __shared__ int candList[CAND_CAP];
    __shared__ int ptList[PT_CAP];
    __shared__ __align__(16) float sDist[PT_CAP];
    __shared__ int sMin[4];
    __shared__ int sCnt[4];
    __shared__ float wSum[4];
    __shared__ float sDm;

    const int arow = aIdx[ai];
    const uint4 qa4 = ((const uint4*)(aDataQ + (size_t)arow * 32))[lane & 7];
    if (tid == 0) { candCount = 0; pointCount = 0; }

    // Dm (wave 0 only)
    if (wv == 0) {
        const int r1 = anchor1[ai], r2 = anchor2[ai];
        const float2 x1 = ((const float2*)(out1 + (size_t)r1 * DIMS))[lane];
        const float2 x2 = ((const float2*)(out2 + (size_t)r2 * DIMS))[lane];
        float dm = fabsf(x1.x - x2.x) + fabsf(x1.y - x2.y);
#pragma unroll
        for (int s = 1; s < 64; s <<= 1) dm += __shfl_xor(dm, s, 64);
        if (lane == 0) sDm = dm + 1.0f;   // GAMMA
    }

    // Phase A: load chunk minima, block min, counted threshold search for E
    const unsigned short* mbase = minIn + ((size_t)side * A_CNT + ai) * NCHUNK;
    int mv[10];
#pragma unroll
    for (int j = 0; j < 10; ++j) {
        const int c = tid + 256 * j;
        mv[j] = (c < NCHUNK_REAL) ? (int)mbase[c] : BIGI;
    }
    int lmin = BIGI;
#pragma unroll
    for (int j = 0; j < 10; ++j) lmin = min(lmin, mv[j]);
#pragma unroll
    for (int s = 1; s < 64; s <<= 1) lmin = min(lmin, __shfl_xor(lmin, s, 64));
    if (lane == 0) sMin[wv] = lmin;
    __syncthreads();
    const int m1 = min(min(sMin[0], sMin[1]), min(sMin[2], sMin[3]));

    int E = m1 + 192;
    for (;;) {
        int c = 0;
#pragma unroll
        for (int j = 0; j < 10; ++j) c += (mv[j] <= E) ? 1 : 0;
#pragma unroll
        for (int s = 1; s < 64; s <<= 1) c += __shfl_xor(c, s, 64);
        if (lane == 0) sCnt[wv] = c;
        __syncthreads();
        const int total = sCnt[0] + sCnt[1] + sCnt[2] + sCnt[3];
        __syncthreads();
        if (total >= KNEG) break;
        E += 192;
    }
    int lo = (E == m1 + 192) ? (m1 - 1) : (E - 192);
    int hi = E;
#pragma unroll
    for (int it = 0; it < 3; ++it) {
        const int mid = (lo + hi) >> 1;
        int c = 0;
#pragma unroll
        for (int j = 0; j < 10; ++j) c += (mv[j] <= mid) ? 1 : 0;
#pragma unroll
        for (int s = 1; s < 64; s <<= 1) c += __shfl_xor(c, s, 64);
        if (lane == 0) sCnt[wv] = c;
        __syncthreads();
        const int total = sCnt[0] + sCnt[1] + sCnt[2] + sCnt[3];
        __syncthreads();
        if (total >= KNEG) hi = mid; else lo = mid;
    }
    const float Rmax = __uint_as_float(*rmaxBits);
    const float thr = (float)hi + 2.0f * Ranc[arow] + 2.0f * Rmax + 4.0f;

    // Phase B: candidate chunks
#pragma unroll
    for (int j = 0; j < 10; ++j) {
        const int c = tid + 256 * j;
        if (c < NCHUNK_REAL && (float)mv[j] <= thr) {
            const int pos = atomicAdd(&candCount, 1);
            if (pos < CAND_CAP) candList[pos] = c;
        }
    }
    __syncthreads();
    const int cc = min(candCount, CAND_CAP);

    // Phase C: per-point u8 SAD filter, 4 chunks in flight per wave iteration.
    const int psub = lane >> 3;
    const int seg  = lane & 7;
    for (int s0 = wv * 4; s0 < cc; s0 += 16) {
        uint4 qp[4];
        int ptv[4];
#pragma unroll
        for (int u = 0; u < 4; ++u) {
            const int s = s0 + u;
            const int c = candList[(s < cc) ? s : s0];   // dup-load for tail, output guarded
            ptv[u] = c * 8 + psub;                       // c < 2500 -> pt < 20000 always
            qp[u] = ((const uint4*)(pDataQ + (size_t)ptv[u] * 32))[seg];
        }
#pragma unroll
        for (int u = 0; u < 4; ++u) {
            unsigned int d = sad_u8(qa4.x, qp[u].x, 0u);
            d = sad_u8(qa4.y, qp[u].y, d);
            d = sad_u8(qa4.z, qp[u].z, d);
            d = sad_u8(qa4.w, qp[u].w, d);
            int di = (int)d;
            di += __shfl_xor(di, 1, 64);
            di += __shfl_xor(di, 2, 64);
            di += __shfl_xor(di, 4, 64);
            if ((s0 + u) < cc && seg == 0 && (float)di <= thr) {
                const int pos = atomicAdd(&pointCount, 1);
                if (pos < PT_CAP) ptList[pos] = ptv[u];
            }
        }
    }
    __syncthreads();
    const int pc = min(pointCount, PT_CAP);

    // Phase D: exact fp32 distances, 4 threads per point; anchor slice in regs.
    const int pt4 = tid >> 2;
    const int qq  = tid & 3;
    float4 av[8];
    {
        const float4* aF4 = (const float4*)(aDataF + (size_t)arow * DIMS) + qq * 8;
#pragma unroll
        for (int q = 0; q < 8; ++q) av[q] = aF4[q];
    }
    for (int base = 0; base < pc; base += 64) {
        const int idx = base + pt4;
        float s01 = 0.f, s23 = 0.f;
        if (idx < pc) {
            const int pt = ptList[idx];
            const float4* p4 = (const float4*)(pDataF + (size_t)pt * DIMS) + qq * 8;
#pragma unroll
            for (int q = 0; q < 8; ++q) {
                const float4 pv = p4[q];
                s01 += fabsf(av[q].x - pv.x) + fabsf(av[q].y - pv.y);
                s23 += fabsf(av[q].z - pv.z) + fabsf(av[q].w - pv.w);
            }
        }
        float s = s01 + s23;
        s += __shfl_xor(s, 1, 64);
        s += __shfl_xor(s, 2, 64);
        if (qq == 0 && idx < pc) sDist[idx] = s;
    }
    __syncthreads();

    // Rank-count top-10 (lexicographic (value,index) -> unique ranks, exactly
    // KNEG slots rank < KNEG; pc >= 10 guaranteed). Block-uniform 1-slot fast
    // path when pc <= 256; float2 LDS reads halve the loop's LDS instrs.
    const float dm = sDm;
    float contrib = 0.f;
    if (pc <= 256) {
        const int i0 = tid;
        const float v0 = (i0 < pc) ? sDist[i0] : BIGV;
        int r0 = 0;
        int j = 0;
        for (; j + 2 <= pc; j += 2) {
            const float2 vj = *(const float2*)&sDist[j];
            r0 += ((vj.x < v0) || (vj.x == v0 && j < i0)) ? 1 : 0;
            r0 += ((vj.y < v0) || (vj.y == v0 && (j + 1) < i0)) ? 1 : 0;
        }
        if (j < pc) {
            const float vj = sDist[j];
            r0 += ((vj < v0) || (vj == v0 && j < i0)) ? 1 : 0;
        }
        if (i0 < pc && r0 < KNEG) contrib = fmaxf(dm - v0, 0.f);
    } else {
        const int i0 = tid, i1 = tid + 256, i2 = tid + 512;
        float v0 = BIGV, v1 = BIGV, v2 = BIGV;
        if (i0 < pc) v0 = sDist[i0];
        if (i1 < pc) v1 = sDist[i1];
        if (i2 < pc) v2 = sDist[i2];
        int r0 = 0, r1 = 0, r2 = 0;
        for (int j = 0; j < pc; ++j) {
            const float vj = sDist[j];
            r0 += (vj < v0) || (vj == v0 && j < i0);
            r1 += (vj < v1) || (vj == v1 && j < i1);
            r2 += (vj < v2) || (vj == v2 && j < i2);
        }
        if (i0 < pc && r0 < KNEG) contrib += fmaxf(dm - v0, 0.f);
        if (i1 < pc && r1 < KNEG) contrib += fmaxf(dm - v1, 0.f);
        if (i2 < pc && r2 < KNEG) contrib += fmaxf(dm - v2, 0.f);
    }
#pragma unroll
    for (int s = 1; s < 64; s <<= 1) contrib += __shfl_xor(contrib, s, 64);
    if (lane == 0) wSum[wv] = contrib;
    __syncthreads();
    if (tid == 0)
        atomicAdd(out, (wSum[0] + wSum[1] + wSum[2] + wSum[3]) * (1.0f / (A_CNT * KNEG)));
}

extern "C" void kernel_launch(void* const* d_in, const int* in_sizes, int n_in,
                              void* d_out, int out_size, void* d_ws, size_t ws_size,
                              hipStream_t stream) {
    const float* out1    = (const float*)d_in[0];
    const float* out2    = (const float*)d_in[1];
    const int*   anchor1 = (const int*)d_in[2];
    const int*   anchor2 = (const int*)d_in[3];
    float* out = (float*)d_out;

    // ws: q1 | q2 | minbuf u16 | R1 | R2 | amax | rmax  (~15.6 MB)
    unsigned int* q1 = (unsigned int*)d_ws;
    unsigned int* q2 = q1 + (size_t)N_PTS * DIMS / 4;
    unsigned short* minbuf = (unsigned short*)(q2 + (size_t)N_PTS * DIMS / 4);
    float* R1 = (float*)(minbuf + (size_t)2 * A_CNT * NCHUNK);
    float* R2 = R1 + N_PTS;
    unsigned int* amax = (unsigned int*)(R2 + N_PTS);
    unsigned int* rmax = amax + 1;

    hipMemsetAsync(out, 0, sizeof(float), stream);
    hipMemsetAsync(amax, 0, 2 * sizeof(unsigned int), stream);

    hipLaunchKernelGGL(absmax_kernel, dim3(1024), dim3(256), 0, stream, out1, out2, amax);
    const int qblocks = (N_PTS * 8 + 255) / 256;   // 8 threads per row
    hipLaunchKernelGGL(quantR_kernel, dim3(qblocks, 2), dim3(256), 0, stream,
                       out1, out2, q1, q2, R1, R2, amax, rmax);

    dim3 gridA(NTILES, 8, 2);
    hipLaunchKernelGGL(dist_sad_kernel, gridA, dim3(256), 0, stream,
                       q1, q2, anchor1, anchor2, minbuf);
    hipLaunchKernelGGL(select_kernel, dim3(2048), dim3(256), 0, stream,
                       out1, out2, q1, q2, anchor1, anchor2, minbuf, R1, R2, rmax, out);
}

// Round 3
// 206.044 us; speedup vs baseline: 1.5042x; 1.5042x over previous
//
#include <hip/hip_runtime.h>

#define N_PTS 20000
#define DIMS  128
#define A_CNT 1024
#define KNEG  10
#define NTILES 157              // ceil(20000/128)
#define NCHUNK (NTILES * 16)    // 2512 chunk-of-8 slots per (side, anchor)
#define NCHUNK_REAL 2500        // 20000/8 — chunks >=2500 are pure padding
#define BIGV  1e18f
#define BIGI  0x7F000000
#define CAND_CAP 768
#define PT_CAP   768
#define AB_BLOCKS 1024          // absmax grid = wsAmax slots
#define QR_BLOCKS 625           // quantR x-grid; 625*256/8 = 20000 rows exactly
#define RPART     1250          // quantR partial-Rmax slots (625 * 2 sides)

// v_sad_u8: d = c + sum_{i=0..3} |a.byte[i] - b.byte[i]|  (4 dims per VALU op)
__device__ __forceinline__ unsigned int sad_u8(unsigned int a, unsigned int b, unsigned int c) {
#if __has_builtin(__builtin_amdgcn_sad_u8)
    return __builtin_amdgcn_sad_u8(a, b, c);
#else
    unsigned int d;
    asm("v_sad_u8 %0, %1, %2, %3" : "=v"(d) : "v"(a), "v"(b), "v"(c));
    return d;
#endif
}

// ---------------------------------------------------------------------------
// absmax: per-BLOCK maxes to wsAmax (no atomics -> no memset dispatch).
// Block 0 also zeroes the output accumulator (stream order covers select).
// ---------------------------------------------------------------------------
__global__ void absmax_kernel(const float* __restrict__ a, const float* __restrict__ b,
                              float* __restrict__ wsAmax, float* __restrict__ outZero) {
    __shared__ float sm[4];
    const int n4 = N_PTS * DIMS / 4;
    const int stride = gridDim.x * blockDim.x;
    float m = 0.f;
    for (int i = blockIdx.x * blockDim.x + threadIdx.x; i < 2 * n4; i += stride) {
        const float4 v = (i < n4) ? ((const float4*)a)[i] : ((const float4*)b)[i - n4];
        m = fmaxf(m, fmaxf(fmaxf(fabsf(v.x), fabsf(v.y)), fmaxf(fabsf(v.z), fabsf(v.w))));
    }
#pragma unroll
    for (int s = 1; s < 64; s <<= 1) m = fmaxf(m, __shfl_xor(m, s, 64));
    if ((threadIdx.x & 63) == 0) sm[threadIdx.x >> 6] = m;
    __syncthreads();
    if (threadIdx.x == 0) {
        wsAmax[blockIdx.x] = fmaxf(fmaxf(sm[0], sm[1]), fmaxf(sm[2], sm[3]));
        if (blockIdx.x == 0) *outZero = 0.f;
    }
}

// ---------------------------------------------------------------------------
// quantize q = rint(127*v/M + 127) in [0,254]; per-row residual R to Rrow;
// per-BLOCK Rmax to wsRmaxPart (no atomics). M is reduced from wsAmax by every
// block (4KB L2 read, hidden). 8 threads/row; grid (625, 2) = exactly 20000
// rows per side -> no early return, block-wide barriers safe.
// ---------------------------------------------------------------------------
__global__ void quantR_kernel(const float* __restrict__ o1, const float* __restrict__ o2,
                              unsigned int* __restrict__ q1, unsigned int* __restrict__ q2,
                              float* __restrict__ Ra, float* __restrict__ Rb,
                              const float* __restrict__ wsAmax,
                              float* __restrict__ wsRmaxPart) {
    __shared__ float sm[4];
    __shared__ float sM;
    const int tid = threadIdx.x;
    // reduce global absmax from the 1024 partials
    {
        const float4 v = ((const float4*)wsAmax)[tid];     // 256 * 4 = 1024
        float m = fmaxf(fmaxf(v.x, v.y), fmaxf(v.z, v.w));
#pragma unroll
        for (int s = 1; s < 64; s <<= 1) m = fmaxf(m, __shfl_xor(m, s, 64));
        if ((tid & 63) == 0) sm[tid >> 6] = m;
        __syncthreads();
        if (tid == 0) sM = fmaxf(fmaxf(sm[0], sm[1]), fmaxf(sm[2], sm[3]));
        __syncthreads();
    }
    const float M = sM;
    const float s = 127.0f / M;

    const int side = blockIdx.y;
    const float* src = side ? o2 : o1;
    unsigned int* dst = side ? q2 : q1;
    float* Rrow = side ? Rb : Ra;
    const int g = blockIdx.x * 256 + tid;
    const int row = g >> 3;                 // always < N_PTS (exact grid)
    const int sub = g & 7;
    const float4* s4 = (const float4*)(src + (size_t)row * DIMS + sub * 16);
    unsigned int* d = dst + (size_t)row * 32 + sub * 4;
    float rs = 0.f;
#pragma unroll
    for (int m = 0; m < 4; ++m) {
        const float4 v = s4[m];
        const float f0 = v.x * s + 127.0f, f1 = v.y * s + 127.0f;
        const float f2 = v.z * s + 127.0f, f3 = v.w * s + 127.0f;
        const float q0 = rintf(f0), q1v = rintf(f1), q2v = rintf(f2), q3 = rintf(f3);
        rs += fabsf(q0 - f0) + fabsf(q1v - f1) + fabsf(q2v - f2) + fabsf(q3 - f3);
        d[m] = (unsigned int)q0 | ((unsigned int)q1v << 8) |
               ((unsigned int)q2v << 16) | ((unsigned int)q3 << 24);
    }
    // butterfly over the 8-thread row group: ALL 8 lanes end with the row sum
    rs += __shfl_xor(rs, 1, 64);
    rs += __shfl_xor(rs, 2, 64);
    rs += __shfl_xor(rs, 4, 64);
    const float R = rs + 1.0f;              // margin for fp rounding in s*v
    if (sub == 0) Rrow[row] = R;
    // block Rmax -> partial slot (no atomics)
    float rm = R;
    rm = fmaxf(rm, __shfl_xor(rm, 8, 64));
    rm = fmaxf(rm, __shfl_xor(rm, 16, 64));
    rm = fmaxf(rm, __shfl_xor(rm, 32, 64));
    if ((tid & 63) == 0) sm[tid >> 6] = rm;
    __syncthreads();
    if (tid == 0)
        wsRmaxPart[blockIdx.y * QR_BLOCKS + blockIdx.x] =
            fmaxf(fmaxf(sm[0], sm[1]), fmaxf(sm[2], sm[3]));
}

// ---------------------------------------------------------------------------
// SAD distance kernel: 64 anchors x 128 points per block, 4x8 per thread.
// REVERTED to the round-0/1 measured-good shape: the 8x8 @(256,2) variant
// regressed ~35us — 2 waves/SIMD cannot hide ~120cy ds_read_b128 latency.
// acc[4][8]=32 + A-frag 16 + P-frag 32 regs ~= 110 VGPR -> 4 waves/SIMD,
// no AGPR accumulator traffic. Block (0,0,0) additionally reduces the 1250
// quantR R-partials into the rmax scalar consumed by select (dispatch-ordered).
// ---------------------------------------------------------------------------
__global__ __launch_bounds__(256, 4)
void dist_sad_kernel(const unsigned int* __restrict__ q1, const unsigned int* __restrict__ q2,
                     const int* __restrict__ anchor1, const int* __restrict__ anchor2,
                     unsigned short* __restrict__ minOut,
                     const float* __restrict__ wsRmaxPart, float* __restrict__ rmaxOut) {
    __shared__ unsigned int sA[64 * 32];
    __shared__ unsigned int sP[128 * 32];

    const int tile = blockIdx.x;    // 0..156
    const int ag   = blockIdx.y;    // 0..15 (groups of 64 anchors)
    const int side = blockIdx.z;    // 0..1

    if (tile == 0 && ag == 0 && side == 0 && threadIdx.x < 64) {
        float r = 0.f;
        for (int i = threadIdx.x; i < RPART; i += 64) r = fmaxf(r, wsRmaxPart[i]);
#pragma unroll
        for (int s = 1; s < 64; s <<= 1) r = fmaxf(r, __shfl_xor(r, s, 64));
        if (threadIdx.x == 0) *rmaxOut = r;
    }

    const unsigned int* aData = side ? q2 : q1;
    const unsigned int* pData = side ? q1 : q2;
    const int*          aIdx  = side ? anchor2 : anchor1;

    const int tid = threadIdx.x;
    const int tx = tid & 15;        // point chunk (8 pts)
    const int ty = tid >> 4;        // anchor chunk (4 anchors)

    // staging A: 64 rows, 4 threads/row, 2 uint4 each (blocks qa, qa+4)
    {
        const int ra = tid >> 2;
        const int qa = tid & 3;
        const unsigned int* aRow = aData + (size_t)aIdx[ag * 64 + ra] * 32;
        const uint4 v0 = *(const uint4*)(aRow + qa * 4);
        const uint4 v1 = *(const uint4*)(aRow + (qa + 4) * 4);
        const int rot = ra >> 3;
        *(uint4*)&sA[ra * 32 + (((qa + rot) & 7) << 2)]     = v0;
        *(uint4*)&sA[ra * 32 + (((qa + 4 + rot) & 7) << 2)] = v1;
    }
    // staging P: 128 rows, 2 threads/row, 4 uint4 each
    {
        const int rp = tid >> 1;
        const int h  = tid & 1;
        const int prow = tile * 128 + rp;
        const bool pvalid = prow < N_PTS;
        const uint4* pRow4 = (const uint4*)(pData + (size_t)prow * 32 + h * 16);
        const int rot = rp >> 3;
#pragma unroll
        for (int j = 0; j < 4; ++j) {
            const uint4 v = pvalid ? pRow4[j]
                                   : make_uint4(0xFFFFFFFFu, 0xFFFFFFFFu, 0xFFFFFFFFu, 0xFFFFFFFFu);
            const int blk = h * 4 + j;
            *(uint4*)&sP[rp * 32 + (((blk + rot) & 7) << 2)] = v;
        }
    }
    __syncthreads();

    unsigned int acc[4][8];
#pragma unroll
    for (int i = 0; i < 4; ++i)
#pragma unroll
        for (int j = 0; j < 8; ++j) acc[i][j] = 0u;

    const int ty4 = ty * 4;
    const int tx8 = tx * 8;

#pragma unroll 2
    for (int bk = 0; bk < 8; ++bk) {
        uint4 A[4], P[8];
        const int aslot = ((bk + (ty >> 1)) & 7) << 2;   // rot(ty*4+i) = ty>>1
        const int pslot = ((bk + tx) & 7) << 2;          // rot(tx*8+j) = tx
#pragma unroll
        for (int i = 0; i < 4; ++i) A[i] = *(const uint4*)&sA[(ty4 + i) * 32 + aslot];
#pragma unroll
        for (int j = 0; j < 8; ++j) P[j] = *(const uint4*)&sP[(tx8 + j) * 32 + pslot];
#pragma unroll
        for (int i = 0; i < 4; ++i)
#pragma unroll
            for (int j = 0; j < 8; ++j) {
                unsigned int s = sad_u8(A[i].x, P[j].x, acc[i][j]);
                s = sad_u8(A[i].y, P[j].y, s);
                s = sad_u8(A[i].z, P[j].z, s);
                acc[i][j] = sad_u8(A[i].w, P[j].w, s);
            }
    }

    const size_t outBase = (size_t)side * A_CNT * NCHUNK;
#pragma unroll
    for (int i = 0; i < 4; ++i) {
        unsigned int m = min(min(min(acc[i][0], acc[i][1]), min(acc[i][2], acc[i][3])),
                             min(min(acc[i][4], acc[i][5]), min(acc[i][6], acc[i][7])));
        minOut[outBase + (size_t)(ag * 64 + ty4 + i) * NCHUNK + tile * 16 + tx] =
            (unsigned short)m;
    }
}

// ---------------------------------------------------------------------------
// select: one 256-thread block (4 waves) per (side, anchor).
//  A: block-min of chunk minima + counted threshold search for E with
//     count(chunkmin <= E) >= 10 (3 bisection steps, E within 24 of true m10).
//     Correctness: >=10 points with d_int <= E -> s*D10 <= E+Ra+Rmax ->
//     top-10 p: d_int(p) <= E + 2(Ra+Rmax).  thr = E + 2Ra + 2Rmax + 4.
//  B: candidate chunks; C: u8 SAD filter, 4 chunks in flight per wave;
//  D: exact fp32 recompute, 4 threads/point, anchor slice in registers;
//  E: rank-count top-10 -> loss. Exact result.
// ---------------------------------------------------------------------------
__global__ __launch_bounds__(256, 4)
void select_kernel(const float* __restrict__ out1, const float* __restrict__ out2,
                   const unsigned int* __restrict__ q1, const unsigned int* __restrict__ q2,
                   const int* __restrict__ anchor1, const int* __restrict__ anchor2,
                   const unsigned short* __restrict__ minIn,
                   const float* __restrict__ R1, const float* __restrict__ R2,
                   const float* __restrict__ rmaxIn, float* __restrict__ out) {
    const int bid = blockIdx.x;          // 0..2047
    const int side = bid >> 10;
    const int ai = bid & 1023;
    const int tid = threadIdx.x;
    const int lane = tid & 63;
    const int wv = tid >> 6;

    const float* aDataF = side ? out2 : out1;
    const float* pDataF = side ? out1 : out2;
    const unsigned int* aDataQ = side ? q2 : q1;
    const unsigned int* pDataQ = side ? q1 : q2;
    const float* Ranc = side ? R2 : R1;
    const int* aIdx = side ? anchor2 : anchor1;

    __shared__ int candCount, pointCount;
    __shared__ int candList[CAND_CAP];
    __shared__ int ptList[PT_CAP];
    __shared__ __align__(16) float sDist[PT_CAP];
    __shared__ int sMin[4];
    __shared__ int sCnt[4];
    __shared__ float wSum[4];
    __shared__ float sDm;

    const int arow = aIdx[ai];
    const uint4 qa4 = ((const uint4*)(aDataQ + (size_t)arow * 32))[lane & 7];
    if (tid == 0) { candCount = 0; pointCount = 0; }

    // Dm (wave 0 only)
    if (wv == 0) {
        const int r1 = anchor1[ai], r2 = anchor2[ai];
        const float2 x1 = ((const float2*)(out1 + (size_t)r1 * DIMS))[lane];
        const float2 x2 = ((const float2*)(out2 + (size_t)r2 * DIMS))[lane];
        float dm = fabsf(x1.x - x2.x) + fabsf(x1.y - x2.y);
#pragma unroll
        for (int s = 1; s < 64; s <<= 1) dm += __shfl_xor(dm, s, 64);
        if (lane == 0) sDm = dm + 1.0f;   // GAMMA
    }

    // Phase A: load chunk minima, block min, counted threshold search for E
    const unsigned short* mbase = minIn + ((size_t)side * A_CNT + ai) * NCHUNK;
    int mv[10];
#pragma unroll
    for (int j = 0; j < 10; ++j) {
        const int c = tid + 256 * j;
        mv[j] = (c < NCHUNK_REAL) ? (int)mbase[c] : BIGI;
    }
    int lmin = BIGI;
#pragma unroll
    for (int j = 0; j < 10; ++j) lmin = min(lmin, mv[j]);
#pragma unroll
    for (int s = 1; s < 64; s <<= 1) lmin = min(lmin, __shfl_xor(lmin, s, 64));
    if (lane == 0) sMin[wv] = lmin;
    __syncthreads();
    const int m1 = min(min(sMin[0], sMin[1]), min(sMin[2], sMin[3]));

    int E = m1 + 192;
    for (;;) {
        int c = 0;
#pragma unroll
        for (int j = 0; j < 10; ++j) c += (mv[j] <= E) ? 1 : 0;
#pragma unroll
        for (int s = 1; s < 64; s <<= 1) c += __shfl_xor(c, s, 64);
        if (lane == 0) sCnt[wv] = c;
        __syncthreads();
        const int total = sCnt[0] + sCnt[1] + sCnt[2] + sCnt[3];
        __syncthreads();
        if (total >= KNEG) break;
        E += 192;
    }
    int lo = (E == m1 + 192) ? (m1 - 1) : (E - 192);
    int hi = E;
#pragma unroll
    for (int it = 0; it < 3; ++it) {
        const int mid = (lo + hi) >> 1;
        int c = 0;
#pragma unroll
        for (int j = 0; j < 10; ++j) c += (mv[j] <= mid) ? 1 : 0;
#pragma unroll
        for (int s = 1; s < 64; s <<= 1) c += __shfl_xor(c, s, 64);
        if (lane == 0) sCnt[wv] = c;
        __syncthreads();
        const int total = sCnt[0] + sCnt[1] + sCnt[2] + sCnt[3];
        __syncthreads();
        if (total >= KNEG) hi = mid; else lo = mid;
    }
    const float Rmax = *rmaxIn;
    const float thr = (float)hi + 2.0f * Ranc[arow] + 2.0f * Rmax + 4.0f;

    // Phase B: candidate chunks
#pragma unroll
    for (int j = 0; j < 10; ++j) {
        const int c = tid + 256 * j;
        if (c < NCHUNK_REAL && (float)mv[j] <= thr) {
            const int pos = atomicAdd(&candCount, 1);
            if (pos < CAND_CAP) candList[pos] = c;
        }
    }
    __syncthreads();
    const int cc = min(candCount, CAND_CAP);

    // Phase C: per-point u8 SAD filter, 4 chunks in flight per wave iteration.
    const int psub = lane >> 3;
    const int seg  = lane & 7;
    for (int s0 = wv * 4; s0 < cc; s0 += 16) {
        uint4 qp[4];
        int ptv[4];
#pragma unroll
        for (int u = 0; u < 4; ++u) {
            const int s = s0 + u;
            const int c = candList[(s < cc) ? s : s0];   // dup-load for tail, output guarded
            ptv[u] = c * 8 + psub;                       // c < 2500 -> pt < 20000 always
            qp[u] = ((const uint4*)(pDataQ + (size_t)ptv[u] * 32))[seg];
        }
#pragma unroll
        for (int u = 0; u < 4; ++u) {
            unsigned int d = sad_u8(qa4.x, qp[u].x, 0u);
            d = sad_u8(qa4.y, qp[u].y, d);
            d = sad_u8(qa4.z, qp[u].z, d);
            d = sad_u8(qa4.w, qp[u].w, d);
            int di = (int)d;
            di += __shfl_xor(di, 1, 64);
            di += __shfl_xor(di, 2, 64);
            di += __shfl_xor(di, 4, 64);
            if ((s0 + u) < cc && seg == 0 && (float)di <= thr) {
                const int pos = atomicAdd(&pointCount, 1);
                if (pos < PT_CAP) ptList[pos] = ptv[u];
            }
        }
    }
    __syncthreads();
    const int pc = min(pointCount, PT_CAP);

    // Phase D: exact fp32 distances, 4 threads per point; anchor slice in regs.
    const int pt4 = tid >> 2;
    const int qq  = tid & 3;
    float4 av[8];
    {
        const float4* aF4 = (const float4*)(aDataF + (size_t)arow * DIMS) + qq * 8;
#pragma unroll
        for (int q = 0; q < 8; ++q) av[q] = aF4[q];
    }
    for (int base = 0; base < pc; base += 64) {
        const int idx = base + pt4;
        float s01 = 0.f, s23 = 0.f;
        if (idx < pc) {
            const int pt = ptList[idx];
            const float4* p4 = (const float4*)(pDataF + (size_t)pt * DIMS) + qq * 8;
#pragma unroll
            for (int q = 0; q < 8; ++q) {
                const float4 pv = p4[q];
                s01 += fabsf(av[q].x - pv.x) + fabsf(av[q].y - pv.y);
                s23 += fabsf(av[q].z - pv.z) + fabsf(av[q].w - pv.w);
            }
        }
        float s = s01 + s23;
        s += __shfl_xor(s, 1, 64);
        s += __shfl_xor(s, 2, 64);
        if (qq == 0 && idx < pc) sDist[idx] = s;
    }
    __syncthreads();

    // Rank-count top-10 (lexicographic (value,index) -> unique ranks; exactly
    // KNEG slots have rank < KNEG; pc >= 10 guaranteed).
    const float dm = sDm;
    float contrib = 0.f;
    if (pc <= 256) {
        const int i0 = tid;
        const float v0 = (i0 < pc) ? sDist[i0] : BIGV;
        int r0 = 0;
        int j = 0;
        for (; j + 2 <= pc; j += 2) {
            const float2 vj = *(const float2*)&sDist[j];
            r0 += ((vj.x < v0) || (vj.x == v0 && j < i0)) ? 1 : 0;
            r0 += ((vj.y < v0) || (vj.y == v0 && (j + 1) < i0)) ? 1 : 0;
        }
        if (j < pc) {
            const float vj = sDist[j];
            r0 += ((vj < v0) || (vj == v0 && j < i0)) ? 1 : 0;
        }
        if (i0 < pc && r0 < KNEG) contrib = fmaxf(dm - v0, 0.f);
    } else {
        const int i0 = tid, i1 = tid + 256, i2 = tid + 512;
        float v0 = BIGV, v1 = BIGV, v2 = BIGV;
        if (i0 < pc) v0 = sDist[i0];
        if (i1 < pc) v1 = sDist[i1];
        if (i2 < pc) v2 = sDist[i2];
        int r0 = 0, r1 = 0, r2 = 0;
        for (int j = 0; j < pc; ++j) {
            const float vj = sDist[j];
            r0 += (vj < v0) || (vj == v0 && j < i0);
            r1 += (vj < v1) || (vj == v1 && j < i1);
            r2 += (vj < v2) || (vj == v2 && j < i2);
        }
        if (i0 < pc && r0 < KNEG) contrib += fmaxf(dm - v0, 0.f);
        if (i1 < pc && r1 < KNEG) contrib += fmaxf(dm - v1, 0.f);
        if (i2 < pc && r2 < KNEG) contrib += fmaxf(dm - v2, 0.f);
    }
#pragma unroll
    for (int s = 1; s < 64; s <<= 1) contrib += __shfl_xor(contrib, s, 64);
    if (lane == 0) wSum[wv] = contrib;
    __syncthreads();
    if (tid == 0)
        atomicAdd(out, (wSum[0] + wSum[1] + wSum[2] + wSum[3]) * (1.0f / (A_CNT * KNEG)));
}

extern "C" void kernel_launch(void* const* d_in, const int* in_sizes, int n_in,
                              void* d_out, int out_size, void* d_ws, size_t ws_size,
                              hipStream_t stream) {
    const float* out1    = (const float*)d_in[0];
    const float* out2    = (const float*)d_in[1];
    const int*   anchor1 = (const int*)d_in[2];
    const int*   anchor2 = (const int*)d_in[3];
    float* out = (float*)d_out;

    // ws: q1 | q2 | minbuf u16 | R1 | R2 | wsAmax[1024] | wsRmaxPart[1280] | rmax
    unsigned int* q1 = (unsigned int*)d_ws;
    unsigned int* q2 = q1 + (size_t)N_PTS * DIMS / 4;
    unsigned short* minbuf = (unsigned short*)(q2 + (size_t)N_PTS * DIMS / 4);
    float* R1 = (float*)(minbuf + (size_t)2 * A_CNT * NCHUNK);
    float* R2 = R1 + N_PTS;
    float* wsAmax = R2 + N_PTS;              // 16B-aligned (offset 15,569,152)
    float* wsRmaxPart = wsAmax + AB_BLOCKS;
    float* rmax = wsRmaxPart + 1280;

    // 4 dispatches, zero memsets: out zeroed by absmax block 0; amax/rmax via
    // per-block partials (no atomics -> no init), reduced by the consumers.
    hipLaunchKernelGGL(absmax_kernel, dim3(AB_BLOCKS), dim3(256), 0, stream,
                       out1, out2, wsAmax, out);
    hipLaunchKernelGGL(quantR_kernel, dim3(QR_BLOCKS, 2), dim3(256), 0, stream,
                       out1, out2, q1, q2, R1, R2, wsAmax, wsRmaxPart);

    dim3 gridA(NTILES, 16, 2);
    hipLaunchKernelGGL(dist_sad_kernel, gridA, dim3(256), 0, stream,
                       q1, q2, anchor1, anchor2, minbuf, wsRmaxPart, rmax);
    hipLaunchKernelGGL(select_kernel, dim3(2048), dim3(256), 0, stream,
                       out1, out2, q1, q2, anchor1, anchor2, minbuf, R1, R2, rmax, out);
}